// Round 5
// baseline (390.608 us; speedup 1.0000x reference)
//
#include <hip/hip_runtime.h>

#define TT 48
#define DD 32
#define HH 64
#define BB 16384
#define BM 16

typedef __bf16 bf16x8 __attribute__((ext_vector_type(8)));
typedef float f32x4 __attribute__((ext_vector_type(4)));
typedef unsigned short us4 __attribute__((ext_vector_type(4)));

// LDS: 8 tiles of [16 rows][128B]: h hi/lo dbuf, xw hi/lo dbuf = 16 KB
#define HOFF(b, p) (((b) * 2 + (p)) * 2048)
#define XWOFF(b, p) (8192 + ((b) * 2 + (p)) * 2048)
#define MFMA(a, b, c) __builtin_amdgcn_mfma_f32_16x16x32_bf16(a, b, c, 0, 0, 0)

static __device__ __forceinline__ int swz(int row, int kb) {
  return row * 128 + (kb ^ ((row & 7) << 4));
}
static __device__ __forceinline__ unsigned short bfu(float f) {
  __bf16 b = (__bf16)f;
  return __builtin_bit_cast(unsigned short, b);
}
static __device__ __forceinline__ float bff(unsigned short u) {
  return (float)__builtin_bit_cast(__bf16, u);
}
static __device__ __forceinline__ float sigm(float v) {
  return __builtin_amdgcn_rcpf(1.f + __expf(-v));
}
static __device__ __forceinline__ float tanh_f(float v) {
  // 1 - 2/(1+e^{2x}); saturates correctly at +-inf
  return fmaf(-2.f, __builtin_amdgcn_rcpf(1.f + __expf(2.f * v)), 1.f);
}

// ------------------------------------------------------------------
// Kernel 0: split W into bf16 hi/lo, reorder gate rows n' = hg*64 + g*16 + h4
// (orig row = g*64 + hg*16 + h4) so i/f/g/o of one (row,hidx) share a lane.
// ------------------------------------------------------------------
__global__ void prep_kernel(const float* __restrict__ W_ih, const float* __restrict__ W_hh,
                            const float* __restrict__ b_ih, const float* __restrict__ b_hh,
                            unsigned short* __restrict__ Whh_hi, unsigned short* __restrict__ Whh_lo,
                            unsigned short* __restrict__ Wih_hi, unsigned short* __restrict__ Wih_lo,
                            float* __restrict__ bsum) {
  int np = threadIdx.x;  // 256 threads, 1 block
  int hg = np >> 6, g = (np >> 4) & 3, h4 = np & 15;
  int orig = g * 64 + hg * 16 + h4;
  bsum[np] = b_ih[orig] + b_hh[orig];
  for (int k = 0; k < 64; ++k) {
    float w = W_hh[orig * 64 + k];
    unsigned short hi = bfu(w);
    Whh_hi[np * 64 + k] = hi;
    Whh_lo[np * 64 + k] = bfu(w - bff(hi));
  }
  for (int k = 0; k < 32; ++k) {
    float w = W_ih[orig * 32 + k];
    unsigned short hi = bfu(w);
    Wih_hi[np * 32 + k] = hi;
    Wih_lo[np * 32 + k] = bfu(w - bff(hi));
  }
}

// ------------------------------------------------------------------
// Kernel 1: attention. a[b,:] = softmax_d( sum_t x[b,t,d]*w_att[2H+t] )
// (h/c/b_att terms are uniform over d -> softmax-invariant -> dropped).
// ------------------------------------------------------------------
__global__ __launch_bounds__(256) void attn_kernel(const float* __restrict__ x,
                                                   const float* __restrict__ W_att,
                                                   float* __restrict__ out0) {
  int tid = threadIdx.x;
  int b = blockIdx.x * 32 + (tid >> 3);
  int dq = (tid & 7) * 4;
  const float* xb = x + (size_t)b * (TT * DD);
  float px = 0.f, py = 0.f, pz = 0.f, pw = 0.f;
#pragma unroll 4
  for (int t = 0; t < TT; ++t) {
    float w = W_att[2 * HH + t];
    float4 xv = *(const float4*)(xb + t * DD + dq);
    px = fmaf(xv.x, w, px);
    py = fmaf(xv.y, w, py);
    pz = fmaf(xv.z, w, pz);
    pw = fmaf(xv.w, w, pw);
  }
  float m = fmaxf(fmaxf(px, py), fmaxf(pz, pw));
#pragma unroll
  for (int s = 1; s < 8; s <<= 1) m = fmaxf(m, __shfl_xor(m, s));
  float ex = __expf(px - m), ey = __expf(py - m), ez = __expf(pz - m), ew = __expf(pw - m);
  float sum = ex + ey + ez + ew;
#pragma unroll
  for (int s = 1; s < 8; s <<= 1) sum += __shfl_xor(sum, s);
  float inv = __builtin_amdgcn_rcpf(sum);
  float4 a;
  a.x = ex * inv; a.y = ey * inv; a.z = ez * inv; a.w = ew * inv;
  float* o = out0 + (size_t)b * (TT * DD) + dq;
#pragma unroll 4
  for (int t = 0; t < TT; ++t) *(float4*)(o + t * DD) = a;
}

// ------------------------------------------------------------------
// Kernel 2: persistent LSTM recurrence. 1024 blocks x 256 thr, 16 rows/block
// (4 blocks/CU = 16 waves/CU). Wave w owns hidx [16w,16w+16) for all 16 rows,
// all 4 gates. W frags in registers (bf16 hi/lo); h & xw via double-buffered
// swizzled LDS, 1 barrier/step. Split precision: Ahi*Bhi + Alo*Bhi + Ahi*Blo.
// out1 written FULL-LINE via LDS: staging lanes reconstruct h rows and emit
// float4 stores (16 lanes = 256B contiguous row) — no partial-line RMW.
// ------------------------------------------------------------------
__global__ __launch_bounds__(256, 4) void lstm_kernel(
    const float* __restrict__ x, const float* __restrict__ h0, const float* __restrict__ c0,
    const float* __restrict__ a_src,
    const unsigned short* __restrict__ Whh_hi, const unsigned short* __restrict__ Whh_lo,
    const unsigned short* __restrict__ Wih_hi, const unsigned short* __restrict__ Wih_lo,
    const float* __restrict__ bsum, float* __restrict__ out1) {
  __shared__ __align__(16) char smem[16384];
  const int tid = threadIdx.x;
  const int wid = tid >> 6;
  const int l = tid & 63;
  const int h4 = l & 15;
  const int lg = l >> 4;
  const int br0 = blockIdx.x * BM;

  // resident W fragments: whh[g][kchunk][hi/lo], wih[g][hi/lo]
  bf16x8 whh[4][2][2];
  bf16x8 wih[4][2];
#pragma unroll
  for (int g = 0; g < 4; ++g) {
    int np = wid * 64 + g * 16 + h4;
#pragma unroll
    for (int c = 0; c < 2; ++c) {
      whh[g][c][0] = *(const bf16x8*)(Whh_hi + np * 64 + c * 32 + lg * 8);
      whh[g][c][1] = *(const bf16x8*)(Whh_lo + np * 64 + c * 32 + lg * 8);
    }
    wih[g][0] = *(const bf16x8*)(Wih_hi + np * 32 + lg * 8);
    wih[g][1] = *(const bf16x8*)(Wih_lo + np * 32 + lg * 8);
  }
  float b4[4];
#pragma unroll
  for (int g = 0; g < 4; ++g) b4[g] = bsum[wid * 64 + g * 16 + h4];

  // c state in C-tile layout: row = lg*4 + r, col hidx = wid*16 + h4
  f32x4 creg;
#pragma unroll
  for (int r = 0; r < 4; ++r)
    creg[r] = c0[(size_t)(br0 + lg * 4 + r) * HH + wid * 16 + h4];

  // staging thread mapping: row = tid>>4 (0..15), j-pair = (tid&15)*2,
  // h-quad = (tid&15)*4
  const int srow = tid >> 4;
  const int sj = (tid & 15) * 2;
  const int hx = (tid & 15) * 4;
  const int hx2 = hx * 2;  // byte offset of h-quad in LDS row
  const float* xrow = x + (size_t)(br0 + srow) * (TT * DD);
  float2 a2 = *(const float2*)(a_src + (size_t)(br0 + srow) * (TT * DD) + sj);
  float* o1row = out1 + (size_t)(br0 + srow) * (TT * HH) + hx;

  // prologue: h0 -> hbuf[0] (4 h values/thread), xw(t=0) -> xwbuf[0]
  {
    float4 v = *(const float4*)(h0 + (size_t)(br0 + srow) * HH + hx);
    us4 hi, lo;
    unsigned short h;
    h = bfu(v.x); hi.x = h; lo.x = bfu(v.x - bff(h));
    h = bfu(v.y); hi.y = h; lo.y = bfu(v.y - bff(h));
    h = bfu(v.z); hi.z = h; lo.z = bfu(v.z - bff(h));
    h = bfu(v.w); hi.w = h; lo.w = bfu(v.w - bff(h));
    *(us4*)(smem + HOFF(0, 0) + swz(srow, hx2)) = hi;
    *(us4*)(smem + HOFF(0, 1) + swz(srow, hx2)) = lo;
    float2 xv = *(const float2*)(xrow + sj);
    float w0 = xv.x * a2.x, w1 = xv.y * a2.y;
    unsigned short h0b = bfu(w0), h1b = bfu(w1);
    unsigned int hp = (unsigned int)h0b | ((unsigned int)h1b << 16);
    unsigned int lp = (unsigned int)bfu(w0 - bff(h0b)) | ((unsigned int)bfu(w1 - bff(h1b)) << 16);
    *(unsigned int*)(smem + XWOFF(0, 0) + swz(srow, sj * 2)) = hp;
    *(unsigned int*)(smem + XWOFF(0, 1) + swz(srow, sj * 2)) = lp;
  }
  __syncthreads();

  for (int t = 0; t < TT; ++t) {
    const int cur = t & 1, nxt = cur ^ 1;
    // (1) issue next x tile load early
    float2 xv;
    const bool stage = (t + 1 < TT);
    if (stage) xv = *(const float2*)(xrow + (t + 1) * DD + sj);

    // (1b) writeback h_{t-1} -> out1 as full-line float4 stores (reads buf
    // cur, read-only by everyone this iteration; no extra barrier needed)
    if (t > 0) {
      us4 hi = *(const us4*)(smem + HOFF(cur, 0) + swz(srow, hx2));
      us4 lo = *(const us4*)(smem + HOFF(cur, 1) + swz(srow, hx2));
      float4 o0;
      o0.x = bff(hi.x) + bff(lo.x);
      o0.y = bff(hi.y) + bff(lo.y);
      o0.z = bff(hi.z) + bff(lo.z);
      o0.w = bff(hi.w) + bff(lo.w);
      *(float4*)(o1row + (size_t)(t - 1) * HH) = o0;
    }

    // (2) A-fragment reads from current buffers
    bf16x8 ah[2][2], axw[2];
#pragma unroll
    for (int c = 0; c < 2; ++c) {
      ah[c][0] = *(const bf16x8*)(smem + HOFF(cur, 0) + swz(h4, c * 64 + lg * 16));
      ah[c][1] = *(const bf16x8*)(smem + HOFF(cur, 1) + swz(h4, c * 64 + lg * 16));
    }
    axw[0] = *(const bf16x8*)(smem + XWOFF(cur, 0) + swz(h4, lg * 16));
    axw[1] = *(const bf16x8*)(smem + XWOFF(cur, 1) + swz(h4, lg * 16));

    // (3) MFMA
    f32x4 gacc[4];
#pragma unroll
    for (int g = 0; g < 4; ++g) {
      f32x4 acc = {b4[g], b4[g], b4[g], b4[g]};
      acc = MFMA(ah[0][0], whh[g][0][0], acc);
      acc = MFMA(ah[0][1], whh[g][0][0], acc);
      acc = MFMA(ah[0][0], whh[g][0][1], acc);
      acc = MFMA(ah[1][0], whh[g][1][0], acc);
      acc = MFMA(ah[1][1], whh[g][1][0], acc);
      acc = MFMA(ah[1][0], whh[g][1][1], acc);
      acc = MFMA(axw[0], wih[g][0], acc);
      acc = MFMA(axw[1], wih[g][0], acc);
      acc = MFMA(axw[0], wih[g][1], acc);
      gacc[g] = acc;
    }

    // (4) pointwise + h round-trip to LDS
#pragma unroll
    for (int r = 0; r < 4; ++r) {
      float ig = sigm(gacc[0][r]);
      float fg = sigm(gacc[1][r]);
      float gg = tanh_f(gacc[2][r]);
      float og = sigm(gacc[3][r]);
      float cn = fg * creg[r] + ig * gg;
      creg[r] = cn;
      float hn = og * tanh_f(cn);
      const int row = lg * 4 + r;
      unsigned short hb = bfu(hn);
      const int kb = (wid * 16 + h4) * 2;
      *(unsigned short*)(smem + HOFF(nxt, 0) + swz(row, kb)) = hb;
      *(unsigned short*)(smem + HOFF(nxt, 1) + swz(row, kb)) = bfu(hn - bff(hb));
    }

    // (5) finish xw staging for t+1
    if (stage) {
      float w0 = xv.x * a2.x, w1 = xv.y * a2.y;
      unsigned short h0b = bfu(w0), h1b = bfu(w1);
      unsigned int hp = (unsigned int)h0b | ((unsigned int)h1b << 16);
      unsigned int lp = (unsigned int)bfu(w0 - bff(h0b)) | ((unsigned int)bfu(w1 - bff(h1b)) << 16);
      *(unsigned int*)(smem + XWOFF(nxt, 0) + swz(srow, sj * 2)) = hp;
      *(unsigned int*)(smem + XWOFF(nxt, 1) + swz(srow, sj * 2)) = lp;
    }
    __syncthreads();
  }

  // epilogue: writeback h_{TT-1} (sits in buf[TT&1] = buf0)
  {
    us4 hi = *(const us4*)(smem + HOFF(TT & 1, 0) + swz(srow, hx2));
    us4 lo = *(const us4*)(smem + HOFF(TT & 1, 1) + swz(srow, hx2));
    float4 o0;
    o0.x = bff(hi.x) + bff(lo.x);
    o0.y = bff(hi.y) + bff(lo.y);
    o0.z = bff(hi.z) + bff(lo.z);
    o0.w = bff(hi.w) + bff(lo.w);
    *(float4*)(o1row + (size_t)(TT - 1) * HH) = o0;
  }
}

extern "C" void kernel_launch(void* const* d_in, const int* in_sizes, int n_in,
                              void* d_out, int out_size, void* d_ws, size_t ws_size,
                              hipStream_t stream) {
  const float* x = (const float*)d_in[0];
  const float* h0 = (const float*)d_in[1];
  const float* c0 = (const float*)d_in[2];
  const float* W_att = (const float*)d_in[3];
  // d_in[4] = b_att: uniform shift, softmax-invariant -> unused
  const float* W_ih = (const float*)d_in[5];
  const float* W_hh = (const float*)d_in[6];
  const float* b_ih = (const float*)d_in[7];
  const float* b_hh = (const float*)d_in[8];

  float* out0 = (float*)d_out;                // attention [B,T,D]
  float* out1 = out0 + (size_t)BB * TT * DD;  // input_encoded [B,T,H]

  char* ws = (char*)d_ws;
  unsigned short* Whh_hi = (unsigned short*)ws;            // 32768 B
  unsigned short* Whh_lo = (unsigned short*)(ws + 32768);  // 32768 B
  unsigned short* Wih_hi = (unsigned short*)(ws + 65536);  // 16384 B
  unsigned short* Wih_lo = (unsigned short*)(ws + 81920);  // 16384 B
  float* bsum = (float*)(ws + 98304);                      // 1024 B

  prep_kernel<<<1, 256, 0, stream>>>(W_ih, W_hh, b_ih, b_hh,
                                     Whh_hi, Whh_lo, Wih_hi, Wih_lo, bsum);
  attn_kernel<<<BB / 32, 256, 0, stream>>>(x, W_att, out0);
  // kernel 2 reads a[b,d] from the t=0 slice of out0 (== a broadcast)
  lstm_kernel<<<BB / BM, 256, 0, stream>>>(x, h0, c0, out0,
                                           Whh_hi, Whh_lo, Wih_hi, Wih_lo, bsum, out1);
}

// Round 6
// 208.280 us; speedup vs baseline: 1.8754x; 1.8754x over previous
//
#include <hip/hip_runtime.h>

#define TT 48
#define DD 32
#define HH 64
#define BB 16384

typedef __bf16 bf16x8 __attribute__((ext_vector_type(8)));
typedef float f32x4 __attribute__((ext_vector_type(4)));
typedef unsigned short us4 __attribute__((ext_vector_type(4)));

#define MFMA(a, b, c) __builtin_amdgcn_mfma_f32_16x16x32_bf16(a, b, c, 0, 0, 0)

// LDS layout (per block): Wih linearized frags 16 KB | bsum f32 1 KB | 4 wave-private h dbuf tiles
#define WIH_OFF 0
#define BS_OFF 16384
#define HB_OFF 17408
#define HB(w, buf, p) (HB_OFF + (w) * 8192 + (buf) * 4096 + (p) * 2048)

static __device__ __forceinline__ int swz(int row, int kb) {
  return row * 128 + (kb ^ ((row & 7) << 4));
}
static __device__ __forceinline__ unsigned short bfu(float f) {
  __bf16 b = (__bf16)f;
  return __builtin_bit_cast(unsigned short, b);
}
static __device__ __forceinline__ float bff(unsigned short u) {
  return (float)__builtin_bit_cast(__bf16, u);
}
static __device__ __forceinline__ float sigm(float v) {
  return __builtin_amdgcn_rcpf(1.f + __expf(-v));
}
static __device__ __forceinline__ float tanh_f(float v) {
  // 1 - 2/(1+e^{2x}); saturates correctly at +-inf
  return fmaf(-2.f, __builtin_amdgcn_rcpf(1.f + __expf(2.f * v)), 1.f);
}

// ------------------------------------------------------------------
// Kernel 0: linearize W into per-lane MFMA A-fragment order.
// Tile m covers ORIGINAL rows n = m*16 + (q*4+r)  (m = g*4+hq, hidx = hq*16+q*4+r).
// WhhL[((p*16+m)*2+c)*512 + l*8 + j] = split_p(W_hh[m*16+(l&15)][c*32+(l>>4)*8+j])
// WihL[m*512 + l*8 + j]             = hi(W_ih[m*16+(l&15)][(l>>4)*8+j])
// bsum[n] = b_ih[n] + b_hh[n] (original order)
// ------------------------------------------------------------------
__global__ void prep_kernel(const float* __restrict__ W_ih, const float* __restrict__ W_hh,
                            const float* __restrict__ b_ih, const float* __restrict__ b_hh,
                            unsigned short* __restrict__ WhhL, unsigned short* __restrict__ WihL,
                            float* __restrict__ bsum) {
  const int tid = threadIdx.x;  // 256 threads, 1 block
  const int l = tid & 63, qt = tid >> 6;
  const int rowl = l & 15, kq = (l >> 4) * 8;
  for (int p = 0; p < 2; ++p)
    for (int mm = 0; mm < 4; ++mm) {
      const int m = qt * 4 + mm;
      for (int c = 0; c < 2; ++c)
        for (int j = 0; j < 8; ++j) {
          float w = W_hh[(m * 16 + rowl) * 64 + c * 32 + kq + j];
          unsigned short hi = bfu(w);
          WhhL[((p * 16 + m) * 2 + c) * 512 + l * 8 + j] = p ? bfu(w - bff(hi)) : hi;
        }
    }
  for (int mm = 0; mm < 4; ++mm) {
    const int m = qt * 4 + mm;
    for (int j = 0; j < 8; ++j)
      WihL[m * 512 + l * 8 + j] = bfu(W_ih[(m * 16 + rowl) * 32 + kq + j]);
  }
  bsum[tid] = b_ih[tid] + b_hh[tid];
}

// ------------------------------------------------------------------
// Kernel 1: attention. a[b,:] = softmax_d( sum_t x[b,t,d]*w_att[2H+t] )
// (h/c/b_att terms are uniform over d -> softmax-invariant -> dropped).
// ------------------------------------------------------------------
__global__ __launch_bounds__(256) void attn_kernel(const float* __restrict__ x,
                                                   const float* __restrict__ W_att,
                                                   float* __restrict__ out0) {
  int tid = threadIdx.x;
  int b = blockIdx.x * 32 + (tid >> 3);
  int dq = (tid & 7) * 4;
  const float* xb = x + (size_t)b * (TT * DD);
  float px = 0.f, py = 0.f, pz = 0.f, pw = 0.f;
#pragma unroll 4
  for (int t = 0; t < TT; ++t) {
    float w = W_att[2 * HH + t];
    float4 xv = *(const float4*)(xb + t * DD + dq);
    px = fmaf(xv.x, w, px);
    py = fmaf(xv.y, w, py);
    pz = fmaf(xv.z, w, pz);
    pw = fmaf(xv.w, w, pw);
  }
  float m = fmaxf(fmaxf(px, py), fmaxf(pz, pw));
#pragma unroll
  for (int s = 1; s < 8; s <<= 1) m = fmaxf(m, __shfl_xor(m, s));
  float ex = __expf(px - m), ey = __expf(py - m), ez = __expf(pz - m), ew = __expf(pw - m);
  float sum = ex + ey + ez + ew;
#pragma unroll
  for (int s = 1; s < 8; s <<= 1) sum += __shfl_xor(sum, s);
  float inv = __builtin_amdgcn_rcpf(sum);
  float4 a;
  a.x = ex * inv; a.y = ey * inv; a.z = ez * inv; a.w = ew * inv;
  float* o = out0 + (size_t)b * (TT * DD) + dq;
#pragma unroll 4
  for (int t = 0; t < TT; ++t) *(float4*)(o + t * DD) = a;
}

// ------------------------------------------------------------------
// Kernel 2: BARRIER-FREE register-resident LSTM. 256 blocks x 256 thr;
// each of the 4 waves owns 16 batch rows end-to-end (no __syncthreads in
// the T loop). A = W (rows = gate-outs), B = [h; a*x] (cols = batch).
// D layout: col = lane&15 = batch, row = (lane>>4)*4+reg = gate-row ->
// i/f/g/o for one (batch,hidx) are lane-local. W_hh hi/lo in 256 VGPRs,
// c in regs, h via wave-private double-buffered swizzled LDS tile
// (intra-wave ds ordering, no barrier). W_ih(hi) + bias from LDS.
// ------------------------------------------------------------------
__global__ __launch_bounds__(256, 1) void lstm_kernel(
    const float* __restrict__ x, const float* __restrict__ h0, const float* __restrict__ c0,
    const float* __restrict__ a_src, const unsigned short* __restrict__ WhhL,
    const unsigned short* __restrict__ WihL, const float* __restrict__ bsumg,
    float* __restrict__ out1) {
  __shared__ __align__(16) char smem[50176];
  const int tid = threadIdx.x;
  const int l = tid & 63;
  const int wid = tid >> 6;
  const int b = l & 15;
  const int qp = l >> 4;
  const int brow = blockIdx.x * 64 + wid * 16 + b;

  // stage Wih frags + bsum into LDS (block-wide, one sync)
  {
    const float4* src = (const float4*)WihL;
    float4* dst = (float4*)(smem + WIH_OFF);
#pragma unroll
    for (int i = 0; i < 4; ++i) dst[tid * 4 + i] = src[tid * 4 + i];
    ((float*)(smem + BS_OFF))[tid] = bsumg[tid];
  }

  // W_hh fragments resident: whh[p][m][c]
  bf16x8 whh[2][16][2];
#pragma unroll
  for (int p = 0; p < 2; ++p)
#pragma unroll
    for (int m = 0; m < 16; ++m)
#pragma unroll
      for (int c = 0; c < 2; ++c)
        whh[p][m][c] = *(const bf16x8*)(WhhL + (((p * 16 + m) * 2 + c) << 9) + l * 8);

  // attention weights for this lane's B-fragment slots
  float av[8];
  {
    const float* ap = a_src + (size_t)brow * (TT * DD) + qp * 8;
    float4 a0 = *(const float4*)ap, a1 = *(const float4*)(ap + 4);
    av[0] = a0.x; av[1] = a0.y; av[2] = a0.z; av[3] = a0.w;
    av[4] = a1.x; av[5] = a1.y; av[6] = a1.z; av[7] = a1.w;
  }

  // c state: creg[hq][r] = c[brow][hq*16+qp*4+r]
  f32x4 creg[4];
#pragma unroll
  for (int hq = 0; hq < 4; ++hq)
    creg[hq] = *(const f32x4*)(c0 + (size_t)brow * HH + hq * 16 + qp * 4);

  // h0 -> hbuf[0] (hi/lo split)
#pragma unroll
  for (int hq = 0; hq < 4; ++hq) {
    float4 v = *(const float4*)(h0 + (size_t)brow * HH + hq * 16 + qp * 4);
    us4 hi, lo;
    unsigned short hh;
    hh = bfu(v.x); hi.x = hh; lo.x = bfu(v.x - bff(hh));
    hh = bfu(v.y); hi.y = hh; lo.y = bfu(v.y - bff(hh));
    hh = bfu(v.z); hi.z = hh; lo.z = bfu(v.z - bff(hh));
    hh = bfu(v.w); hi.w = hh; lo.w = bfu(v.w - bff(hh));
    *(us4*)(smem + HB(wid, 0, 0) + swz(b, hq * 32 + qp * 8)) = hi;
    *(us4*)(smem + HB(wid, 0, 1) + swz(b, hq * 32 + qp * 8)) = lo;
  }
  __syncthreads();  // only for the Wih/bsum staging

  const float* xp = x + (size_t)brow * (TT * DD) + qp * 8;
  float* op = out1 + (size_t)brow * (TT * HH) + qp * 4;
  float xv[8];
  {
    float4 x0 = *(const float4*)xp, x1 = *(const float4*)(xp + 4);
    xv[0] = x0.x; xv[1] = x0.y; xv[2] = x0.z; xv[3] = x0.w;
    xv[4] = x1.x; xv[5] = x1.y; xv[6] = x1.z; xv[7] = x1.w;
  }

  for (int t = 0; t < TT; ++t) {
    const int cur = t & 1;
    // B-frag: xw = a*x (single bf16; lo-correction negligible at |a*x|~0.03)
    bf16x8 bxw;
#pragma unroll
    for (int j = 0; j < 8; ++j) bxw[j] = (__bf16)(xv[j] * av[j]);
    // B-frag: h hi/lo from wave-private LDS
    bf16x8 bh[2][2];
#pragma unroll
    for (int c = 0; c < 2; ++c)
#pragma unroll
      for (int p = 0; p < 2; ++p)
        bh[c][p] = *(const bf16x8*)(smem + HB(wid, cur, p) + swz(b, c * 64 + qp * 16));
    // prefetch next x
    if (t + 1 < TT) {
      const float* xn = xp + (t + 1) * DD;
      float4 x0 = *(const float4*)xn, x1 = *(const float4*)(xn + 4);
      xv[0] = x0.x; xv[1] = x0.y; xv[2] = x0.z; xv[3] = x0.w;
      xv[4] = x1.x; xv[5] = x1.y; xv[6] = x1.z; xv[7] = x1.w;
    }

#pragma unroll
    for (int half = 0; half < 2; ++half) {
      f32x4 acc[4][2];
#pragma unroll
      for (int g = 0; g < 4; ++g)
#pragma unroll
        for (int hqi = 0; hqi < 2; ++hqi) {
          const int hq = half * 2 + hqi, m = g * 4 + hq;
          // bias init: same-address broadcast read (free)
          f32x4 A = *(const f32x4*)(smem + BS_OFF + (m * 16 + qp * 4) * 4);
          A = MFMA(whh[0][m][0], bh[0][0], A);  // Whi*Bhi  k 0..31
          A = MFMA(whh[1][m][0], bh[0][0], A);  // Wlo*Bhi
          A = MFMA(whh[0][m][0], bh[0][1], A);  // Whi*Blo
          A = MFMA(whh[0][m][1], bh[1][0], A);  // k 32..63
          A = MFMA(whh[1][m][1], bh[1][0], A);
          A = MFMA(whh[0][m][1], bh[1][1], A);
          bf16x8 wi = *(const bf16x8*)(smem + WIH_OFF + m * 1024 + l * 16);
          A = MFMA(wi, bxw, A);                 // xw chunk
          acc[g][hqi] = A;
        }
      // pointwise (lane-local i/f/g/o) for this half's 8 elements
#pragma unroll
      for (int hqi = 0; hqi < 2; ++hqi) {
        const int hq = half * 2 + hqi;
        float hr[4];
#pragma unroll
        for (int r = 0; r < 4; ++r) {
          float ig = sigm(acc[0][hqi][r]);
          float fg = sigm(acc[1][hqi][r]);
          float gt = tanh_f(acc[2][hqi][r]);
          float og = sigm(acc[3][hqi][r]);
          float cn = fg * creg[hq][r] + ig * gt;
          creg[hq][r] = cn;
          hr[r] = og * tanh_f(cn);
        }
        float4 hv;
        hv.x = hr[0]; hv.y = hr[1]; hv.z = hr[2]; hv.w = hr[3];
        *(float4*)(op + (size_t)t * HH + hq * 16) = hv;
        us4 hi, lo;
        unsigned short hh;
        hh = bfu(hr[0]); hi.x = hh; lo.x = bfu(hr[0] - bff(hh));
        hh = bfu(hr[1]); hi.y = hh; lo.y = bfu(hr[1] - bff(hh));
        hh = bfu(hr[2]); hi.z = hh; lo.z = bfu(hr[2] - bff(hh));
        hh = bfu(hr[3]); hi.w = hh; lo.w = bfu(hr[3] - bff(hh));
        *(us4*)(smem + HB(wid, cur ^ 1, 0) + swz(b, hq * 32 + qp * 8)) = hi;
        *(us4*)(smem + HB(wid, cur ^ 1, 1) + swz(b, hq * 32 + qp * 8)) = lo;
      }
    }
  }
}

extern "C" void kernel_launch(void* const* d_in, const int* in_sizes, int n_in,
                              void* d_out, int out_size, void* d_ws, size_t ws_size,
                              hipStream_t stream) {
  const float* x = (const float*)d_in[0];
  const float* h0 = (const float*)d_in[1];
  const float* c0 = (const float*)d_in[2];
  const float* W_att = (const float*)d_in[3];
  // d_in[4] = b_att: uniform shift, softmax-invariant -> unused
  const float* W_ih = (const float*)d_in[5];
  const float* W_hh = (const float*)d_in[6];
  const float* b_ih = (const float*)d_in[7];
  const float* b_hh = (const float*)d_in[8];

  float* out0 = (float*)d_out;                // attention [B,T,D]
  float* out1 = out0 + (size_t)BB * TT * DD;  // input_encoded [B,T,H]

  char* ws = (char*)d_ws;
  unsigned short* WhhL = (unsigned short*)ws;            // 65536 B
  unsigned short* WihL = (unsigned short*)(ws + 65536);  // 16384 B
  float* bsum = (float*)(ws + 81920);                    // 1024 B

  prep_kernel<<<1, 256, 0, stream>>>(W_ih, W_hh, b_ih, b_hh, WhhL, WihL, bsum);
  attn_kernel<<<BB / 32, 256, 0, stream>>>(x, W_att, out0);
  // lstm reads a[b,d] from the t=0 slice of out0 (== a broadcast over t)
  lstm_kernel<<<BB / 64, 256, 0, stream>>>(x, h0, c0, out0, WhhL, WihL, bsum, out1);
}

// Round 7
// 190.487 us; speedup vs baseline: 2.0506x; 1.0934x over previous
//
#include <hip/hip_runtime.h>

#define TT 48
#define DD 32
#define HH 64
#define BB 16384

typedef __bf16 bf16x8 __attribute__((ext_vector_type(8)));
typedef float f32x4 __attribute__((ext_vector_type(4)));

#define MFMA(a, b, c) __builtin_amdgcn_mfma_f32_16x16x32_bf16(a, b, c, 0, 0, 0)

static __device__ __forceinline__ unsigned short bfu(float f) {
  __bf16 b = (__bf16)f;
  return __builtin_bit_cast(unsigned short, b);
}
static __device__ __forceinline__ float bff(unsigned short u) {
  return (float)__builtin_bit_cast(__bf16, u);
}
static __device__ __forceinline__ __bf16 bfc(unsigned short u) {
  return __builtin_bit_cast(__bf16, u);
}
static __device__ __forceinline__ float sigm(float v) {
  return __builtin_amdgcn_rcpf(1.f + __expf(-v));
}
static __device__ __forceinline__ float tanh_f(float v) {
  // 1 - 2/(1+e^{2x}); saturates correctly at +-inf
  return fmaf(-2.f, __builtin_amdgcn_rcpf(1.f + __expf(2.f * v)), 1.f);
}

// ------------------------------------------------------------------
// Row bijection: tile m = g*4+hq (g = gate), tile-row = qp*4+r.
//   hidx(hq,qp,r) = (hq>>1)*32 + qp*8 + (hq&1)*4 + r
// With this choice, lane (b,qp)'s D outputs {hidx(hq,qp,r)} == exactly the
// B-fragment slots it must supply next step {c*32+qp*8+j} -> the h state
// NEVER leaves the lane: zero LDS/shuffle in the recurrence.
// ------------------------------------------------------------------

// Kernel 0: linearize W into per-lane MFMA A-fragment order with the bijection.
__global__ void prep_kernel(const float* __restrict__ W_ih, const float* __restrict__ W_hh,
                            const float* __restrict__ b_ih, const float* __restrict__ b_hh,
                            unsigned short* __restrict__ WhhL, unsigned short* __restrict__ WihL,
                            float* __restrict__ bsumL) {
  const int tid = threadIdx.x;  // 256 threads, 1 block
  const int l = tid & 63, qt = tid >> 6;
  const int rowl = l & 15, kq = (l >> 4) * 8;
  for (int mm = 0; mm < 4; ++mm) {
    const int m = qt * 4 + mm;
    const int g = m >> 2, hq = m & 3;
    const int hidx = (hq >> 1) * 32 + (rowl >> 2) * 8 + (hq & 1) * 4 + (rowl & 3);
    const int orig = g * 64 + hidx;
    for (int c = 0; c < 2; ++c)
      for (int j = 0; j < 8; ++j) {
        float w = W_hh[orig * 64 + c * 32 + kq + j];
        unsigned short hi = bfu(w);
        WhhL[((0 * 16 + m) * 2 + c) * 512 + l * 8 + j] = hi;
        WhhL[((1 * 16 + m) * 2 + c) * 512 + l * 8 + j] = bfu(w - bff(hi));
      }
    for (int j = 0; j < 8; ++j)
      WihL[m * 512 + l * 8 + j] = bfu(W_ih[orig * 32 + kq + j]);
    if ((l >> 4) == 0) bsumL[m * 16 + rowl] = b_ih[orig] + b_hh[orig];
  }
}

// ------------------------------------------------------------------
// Kernel 1: attention. a[b,:] = softmax_d( sum_t x[b,t,d]*w_att[2H+t] )
// (h/c/b_att terms are uniform over d -> softmax-invariant -> dropped).
// ------------------------------------------------------------------
__global__ __launch_bounds__(256) void attn_kernel(const float* __restrict__ x,
                                                   const float* __restrict__ W_att,
                                                   float* __restrict__ out0) {
  int tid = threadIdx.x;
  int b = blockIdx.x * 32 + (tid >> 3);
  int dq = (tid & 7) * 4;
  const float* xb = x + (size_t)b * (TT * DD);
  float px = 0.f, py = 0.f, pz = 0.f, pw = 0.f;
#pragma unroll 4
  for (int t = 0; t < TT; ++t) {
    float w = W_att[2 * HH + t];
    float4 xv = *(const float4*)(xb + t * DD + dq);
    px = fmaf(xv.x, w, px);
    py = fmaf(xv.y, w, py);
    pz = fmaf(xv.z, w, pz);
    pw = fmaf(xv.w, w, pw);
  }
  float m = fmaxf(fmaxf(px, py), fmaxf(pz, pw));
#pragma unroll
  for (int s = 1; s < 8; s <<= 1) m = fmaxf(m, __shfl_xor(m, s));
  float ex = __expf(px - m), ey = __expf(py - m), ez = __expf(pz - m), ew = __expf(pw - m);
  float sum = ex + ey + ez + ew;
#pragma unroll
  for (int s = 1; s < 8; s <<= 1) sum += __shfl_xor(sum, s);
  float inv = __builtin_amdgcn_rcpf(sum);
  float4 a;
  a.x = ex * inv; a.y = ey * inv; a.z = ez * inv; a.w = ew * inv;
  float* o = out0 + (size_t)b * (TT * DD) + dq;
#pragma unroll 4
  for (int t = 0; t < TT; ++t) *(float4*)(o + t * DD) = a;
}

// ------------------------------------------------------------------
// Kernel 2: FULLY LANE-LOCAL register-resident LSTM. 256 blocks x 256 thr,
// each wave owns 16 batch rows end-to-end. No ds_write, no barrier, no
// cross-lane exchange in the T loop (h stays in the lane via the row
// bijection). W_hh hi/lo (256 regs) + W_ih (64 regs) + c + h resident.
// Split precision: Whi*Bhi + Wlo*Bhi + Whi*Blo per 32-chunk.
// ------------------------------------------------------------------
__global__ __launch_bounds__(256, 1) void lstm_kernel(
    const float* __restrict__ x, const float* __restrict__ h0, const float* __restrict__ c0,
    const float* __restrict__ a_src, const unsigned short* __restrict__ WhhL,
    const unsigned short* __restrict__ WihL, const float* __restrict__ bsumL,
    float* __restrict__ out1) {
  __shared__ __align__(16) float sbias[256];
  const int tid = threadIdx.x;
  const int l = tid & 63;
  const int wid = tid >> 6;
  const int b = l & 15;
  const int qp = l >> 4;
  const int brow = blockIdx.x * 64 + wid * 16 + b;

  sbias[tid] = bsumL[tid];

  // resident W fragments
  bf16x8 whh[2][16][2];
#pragma unroll
  for (int p = 0; p < 2; ++p)
#pragma unroll
    for (int m = 0; m < 16; ++m)
#pragma unroll
      for (int c = 0; c < 2; ++c)
        whh[p][m][c] = *(const bf16x8*)(WhhL + (((p * 16 + m) * 2 + c) << 9) + l * 8);
  bf16x8 wih[16];
#pragma unroll
  for (int m = 0; m < 16; ++m)
    wih[m] = *(const bf16x8*)(WihL + (m << 9) + l * 8);

  // attention weights for this lane's B-fragment slots (d = qp*8 + j)
  float av[8];
  {
    const float* ap = a_src + (size_t)brow * (TT * DD) + qp * 8;
    float4 a0 = *(const float4*)ap, a1 = *(const float4*)(ap + 4);
    av[0] = a0.x; av[1] = a0.y; av[2] = a0.z; av[3] = a0.w;
    av[4] = a1.x; av[5] = a1.y; av[6] = a1.z; av[7] = a1.w;
  }

  // c state: creg[hq][r] = c[brow][hidx(hq,qp,r)]
  f32x4 creg[4];
#pragma unroll
  for (int hq = 0; hq < 4; ++hq)
    creg[hq] = *(const f32x4*)(c0 + (size_t)brow * HH + (hq >> 1) * 32 + qp * 8 + (hq & 1) * 4);

  // h state as B-fragments: bh[c][p] elem j = split_p(h[brow][c*32+qp*8+j])
  bf16x8 bh[2][2];
#pragma unroll
  for (int c = 0; c < 2; ++c) {
    const float* hp = h0 + (size_t)brow * HH + c * 32 + qp * 8;
    float4 v0 = *(const float4*)hp, v1 = *(const float4*)(hp + 4);
    float vv[8] = {v0.x, v0.y, v0.z, v0.w, v1.x, v1.y, v1.z, v1.w};
#pragma unroll
    for (int j = 0; j < 8; ++j) {
      unsigned short hi = bfu(vv[j]);
      bh[c][0][j] = bfc(hi);
      bh[c][1][j] = bfc(bfu(vv[j] - bff(hi)));
    }
  }
  __syncthreads();  // only for sbias staging

  const float* xp = x + (size_t)brow * (TT * DD) + qp * 8;
  float* op = out1 + (size_t)brow * (TT * HH);
  float xv[8];
  {
    float4 x0 = *(const float4*)xp, x1 = *(const float4*)(xp + 4);
    xv[0] = x0.x; xv[1] = x0.y; xv[2] = x0.z; xv[3] = x0.w;
    xv[4] = x1.x; xv[5] = x1.y; xv[6] = x1.z; xv[7] = x1.w;
  }

  for (int t = 0; t < TT; ++t) {
    // B-frag: xw = a*x (single bf16; lo-correction negligible at |a*x|~0.03)
    bf16x8 bxw;
#pragma unroll
    for (int j = 0; j < 8; ++j) bxw[j] = (__bf16)(xv[j] * av[j]);
    // prefetch next x
    float xn[8];
    if (t + 1 < TT) {
      const float* xnp = xp + (t + 1) * DD;
      float4 x0 = *(const float4*)xnp, x1 = *(const float4*)(xnp + 4);
      xn[0] = x0.x; xn[1] = x0.y; xn[2] = x0.z; xn[3] = x0.w;
      xn[4] = x1.x; xn[5] = x1.y; xn[6] = x1.z; xn[7] = x1.w;
    }

    bf16x8 nbh[2][2];
#pragma unroll
    for (int hq = 0; hq < 4; ++hq) {
      f32x4 acc[4];
#pragma unroll
      for (int g = 0; g < 4; ++g) {
        const int m = g * 4 + hq;
        f32x4 A = *(const f32x4*)(sbias + m * 16 + qp * 4);  // broadcast, conflict-free
        A = MFMA(whh[0][m][0], bh[0][0], A);  // k 0..31: Whi*Bhi
        A = MFMA(whh[1][m][0], bh[0][0], A);  //          Wlo*Bhi
        A = MFMA(whh[0][m][0], bh[0][1], A);  //          Whi*Blo
        A = MFMA(whh[0][m][1], bh[1][0], A);  // k 32..63
        A = MFMA(whh[1][m][1], bh[1][0], A);
        A = MFMA(whh[0][m][1], bh[1][1], A);
        A = MFMA(wih[m], bxw, A);             // input chunk
        acc[g] = A;
      }
      // pointwise: i/f/g/o lane-local (rows qp*4+r of tiles g*4+hq)
      float hr[4];
#pragma unroll
      for (int r = 0; r < 4; ++r) {
        float ig = sigm(acc[0][r]);
        float fg = sigm(acc[1][r]);
        float gt = tanh_f(acc[2][r]);
        float og = sigm(acc[3][r]);
        float cn = fg * creg[hq][r] + ig * gt;
        creg[hq][r] = cn;
        hr[r] = og * tanh_f(cn);
      }
      // out1: contiguous float4 at hidx base (full-line coverage per row)
      float4 hv;
      hv.x = hr[0]; hv.y = hr[1]; hv.z = hr[2]; hv.w = hr[3];
      *(float4*)(op + (size_t)t * HH + (hq >> 1) * 32 + qp * 8 + (hq & 1) * 4) = hv;
      // repack into next step's B-fragment (lane-local, no exchange)
#pragma unroll
      for (int r = 0; r < 4; ++r) {
        unsigned short hb = bfu(hr[r]);
        nbh[hq >> 1][0][(hq & 1) * 4 + r] = bfc(hb);
        nbh[hq >> 1][1][(hq & 1) * 4 + r] = bfc(bfu(hr[r] - bff(hb)));
      }
    }
#pragma unroll
    for (int c = 0; c < 2; ++c) {
      bh[c][0] = nbh[c][0];
      bh[c][1] = nbh[c][1];
    }
#pragma unroll
    for (int j = 0; j < 8; ++j) xv[j] = xn[j];
  }
}

extern "C" void kernel_launch(void* const* d_in, const int* in_sizes, int n_in,
                              void* d_out, int out_size, void* d_ws, size_t ws_size,
                              hipStream_t stream) {
  const float* x = (const float*)d_in[0];
  const float* h0 = (const float*)d_in[1];
  const float* c0 = (const float*)d_in[2];
  const float* W_att = (const float*)d_in[3];
  // d_in[4] = b_att: uniform shift, softmax-invariant -> unused
  const float* W_ih = (const float*)d_in[5];
  const float* W_hh = (const float*)d_in[6];
  const float* b_ih = (const float*)d_in[7];
  const float* b_hh = (const float*)d_in[8];

  float* out0 = (float*)d_out;                // attention [B,T,D]
  float* out1 = out0 + (size_t)BB * TT * DD;  // input_encoded [B,T,H]

  char* ws = (char*)d_ws;
  unsigned short* WhhL = (unsigned short*)ws;            // 65536 B
  unsigned short* WihL = (unsigned short*)(ws + 65536);  // 16384 B
  float* bsumL = (float*)(ws + 81920);                   // 1024 B

  prep_kernel<<<1, 256, 0, stream>>>(W_ih, W_hh, b_ih, b_hh, WhhL, WihL, bsumL);
  attn_kernel<<<BB / 32, 256, 0, stream>>>(x, W_att, out0);
  // lstm reads a[b,d] from the t=0 slice of out0 (== a broadcast over t)
  lstm_kernel<<<BB / 64, 256, 0, stream>>>(x, h0, c0, out0, WhhL, WihL, bsumL, out1);
}